// Round 8
// baseline (600.016 us; speedup 1.0000x reference)
//
#include <hip/hip_runtime.h>
#include <hip/hip_bf16.h>

#define NN 100000
#define EE 1250000

#define RL(x, l) __builtin_amdgcn_readlane((x), (l))
#define RLF(x, l) __int_as_float(__builtin_amdgcn_readlane(__float_as_int(x), (l)))

__device__ __forceinline__ unsigned short bf16rtn(float x) {
    unsigned u = __float_as_uint(x);
    unsigned r = u + 0x7fffu + ((u >> 16) & 1u);
    return (unsigned short)(r >> 16);
}
__device__ __forceinline__ float bflo(unsigned u) { return __uint_as_float(u << 16); }
__device__ __forceinline__ float bfhi(unsigned u) { return __uint_as_float(u & 0xffff0000u); }

// ---------------- CSR build ----------------

// one returning atomic per edge: slot within dst row.
// ~50us floor: memory-side atomics write ~35B to HBM each (R5/R7 measured).
__global__ __launch_bounds__(256) void k_count(const int* __restrict__ ei,
                                               int* __restrict__ cnt,
                                               int* __restrict__ slot) {
    int e = blockIdx.x * 256 + threadIdx.x;
    if (e >= EE) return;
    int d = __builtin_nontemporal_load(&ei[EE + e]);
    int s = atomicAdd(&cnt[d], 1);
    __builtin_nontemporal_store(s, &slot[e]);
}

__global__ __launch_bounds__(256) void k_bsum(const int* __restrict__ cnt, int* __restrict__ bsum) {
    __shared__ int ls[256];
    int b = blockIdx.x, tid = threadIdx.x;
    int base = b * 1024 + tid * 4;
    int s = 0;
    #pragma unroll
    for (int j = 0; j < 4; ++j) { int g = base + j; if (g < NN) s += cnt[g]; }
    ls[tid] = s; __syncthreads();
    for (int off = 128; off > 0; off >>= 1) {
        if (tid < off) ls[tid] += ls[tid + off];
        __syncthreads();
    }
    if (tid == 0) bsum[b] = ls[0];
}

// per-1024 scan; block base computed in-kernel from bsum (merged k_bscan)
__global__ __launch_bounds__(256) void k_scan_out(const int* __restrict__ cnt,
                                                  const int* __restrict__ bsum,
                                                  int* __restrict__ rowptr) {
    __shared__ int ls[256];
    __shared__ int sbase;
    int b = blockIdx.x, tid = threadIdx.x;
    if (tid < 64) {
        int w0 = (tid < b) ? bsum[tid] : 0;
        int w1 = ((64 + tid) < b) ? bsum[64 + tid] : 0;
        int s = w0 + w1;
        #pragma unroll
        for (int m = 32; m >= 1; m >>= 1) s += __shfl_xor(s, m, 64);
        if (tid == 0) sbase = s;
    }
    int base = b * 1024 + tid * 4;
    int c[4]; int s = 0;
    #pragma unroll
    for (int j = 0; j < 4; ++j) {
        int g = base + j;
        c[j] = (g < NN) ? cnt[g] : 0;
        s += c[j];
    }
    ls[tid] = s; __syncthreads();
    for (int off = 1; off < 256; off <<= 1) {
        int v = (tid >= off) ? ls[tid - off] : 0;
        __syncthreads();
        ls[tid] += v;
        __syncthreads();
    }
    int excl = ls[tid] - s + sbase;
    #pragma unroll
    for (int j = 0; j < 4; ++j) {
        int g = base + j;
        if (g < NN) {
            rowptr[g + 1] = excl + c[j];
            excl += c[j];
        }
    }
    if (b == 0 && tid == 0) rowptr[0] = 0;
}

__global__ __launch_bounds__(256) void k_fill(const int* __restrict__ ei,
                                              const float* __restrict__ ew,
                                              const int* __restrict__ slot,
                                              const int* __restrict__ rowptr,
                                              int2* __restrict__ epair) {
    int e = blockIdx.x * 256 + threadIdx.x;
    if (e >= EE) return;
    int s = __builtin_nontemporal_load(&ei[e]);
    int d = __builtin_nontemporal_load(&ei[EE + e]);
    float w = __builtin_nontemporal_load(&ew[e]);
    int sl = __builtin_nontemporal_load(&slot[e]);
    int p = rowptr[d] + sl;
    epair[p] = make_int2(s, __float_as_int(w));
}

// deg[n] = 1 + sum_row ew -> dinv[n], xd[n] = dinv[n]*x[n].  4 nodes/wave.
__global__ __launch_bounds__(256) void k_deg(const int* __restrict__ rowptr,
                                             const int2* __restrict__ epair,
                                             const float* __restrict__ x,
                                             float* __restrict__ dinv,
                                             float* __restrict__ xd) {
    int lane = threadIdx.x & 63;
    int wid  = threadIdx.x >> 6;
    int l16  = lane & 15;
    int sub  = lane >> 4;
    int node = (blockIdx.x * 4 + wid) * 4 + sub;
    if (node >= NN) return;
    int beg = rowptr[node], end = rowptr[node + 1];
    float s = 0.f;
    for (int idx = beg + l16; idx < end; idx += 16)
        s += __int_as_float(epair[idx].y);
    #pragma unroll
    for (int m = 8; m >= 1; m >>= 1) s += __shfl_xor(s, m, 64);
    if (l16 == 0) {
        float di = rsqrtf(s + 1.0f);
        dinv[node] = di;
        xd[node] = di * x[node];
    }
}

// ---------------- Layers ----------------
// Identity: Agg_l[d] = dinv_d * ( G'_l[d] + sum_e w_e * G'_l[src] ), G' = dinv (.) G.
// G' stored in bf16 (64 feats = 32 uints/row). Y and all accumulation fp32.

// Layer 1: z scalar agg + matvec, W2 via LDS (amortized over 4 nodes/wave). grid NN/16.
__global__ __launch_bounds__(256) void k_l1(
    const float* __restrict__ xd, const float* __restrict__ dinv,
    const int* __restrict__ rowptr, const int2* __restrict__ ep,
    const float* __restrict__ W1, const float* __restrict__ b1,
    const float* __restrict__ W2, unsigned short* __restrict__ Gout)
{
    __shared__ float sW[4096];
    int tid = threadIdx.x;
    #pragma unroll
    for (int i = 0; i < 16; ++i) sW[tid + i * 256] = W2[tid + i * 256];
    __syncthreads();
    int lane = tid & 63, l16 = lane & 15, sub = lane >> 4;
    int g4 = blockIdx.x * 4 + (tid >> 6);
    int nodeS = g4 * 4 + sub;
    int beg = rowptr[nodeS], end = rowptr[nodeS + 1];
    float partial = 0.f;
    for (int idx = beg + l16; idx < end; idx += 16) {
        int2 p = ep[idx];
        partial = fmaf(__int_as_float(p.y), xd[p.x], partial);
    }
    #pragma unroll
    for (int m = 8; m >= 1; m >>= 1) partial += __shfl_xor(partial, m, 64);
    float z = dinv[nodeS] * (xd[nodeS] + partial);   // valid where l16==0
    float z0 = RLF(z, 0), z1 = RLF(z, 16), z2 = RLF(z, 32), z3 = RLF(z, 48);
    float w1l = W1[lane], b1l = b1[lane];
    float v0 = fmaxf(fmaf(z0, w1l, b1l), 0.f);
    float v1 = fmaxf(fmaf(z1, w1l, b1l), 0.f);
    float v2 = fmaxf(fmaf(z2, w1l, b1l), 0.f);
    float v3 = fmaxf(fmaf(z3, w1l, b1l), 0.f);
    float a0 = 0.f, a1 = 0.f, a2 = 0.f, a3 = 0.f;
    #pragma unroll
    for (int k = 0; k < 64; ++k) {
        float wk = sW[k * 64 + lane];
        a0 = fmaf(RLF(v0, k), wk, a0);
        a1 = fmaf(RLF(v1, k), wk, a1);
        a2 = fmaf(RLF(v2, k), wk, a2);
        a3 = fmaf(RLF(v3, k), wk, a3);
    }
    int n0 = g4 * 4;
    Gout[(n0 + 0) * 64 + lane] = bf16rtn(dinv[n0 + 0] * a0);
    Gout[(n0 + 1) * 64 + lane] = bf16rtn(dinv[n0 + 1] * a1);
    Gout[(n0 + 2) * 64 + lane] = bf16rtn(dinv[n0 + 2] * a2);
    Gout[(n0 + 3) * 64 + lane] = bf16rtn(dinv[n0 + 3] * a3);
}

// Gather over bf16 rows: Y[d] = dinv_d * ( G'[d] + sum_e w_e * G'[src] ).
// One wave per node; 32 edges per batch = 16 row-loads in flight
// (2 edges per load inst: wave halves). ep reads wave-uniform -> s_load.
// Tail: always a masked 32-batch (clamped dup loads are L1 hits). grid = NN/4.
__global__ __launch_bounds__(256, 6) void k_gather(
    const unsigned* __restrict__ G16, const float* __restrict__ dinv,
    const int* __restrict__ rowptr, const int2* __restrict__ ep,
    float* __restrict__ Y)
{
    int tid = threadIdx.x;
    int lane = tid & 63;
    int lc = lane & 31;
    int half = lane >> 5;
    int node = blockIdx.x * 4 + (tid >> 6);
    int beg = __builtin_amdgcn_readfirstlane(rowptr[node]);
    int end = __builtin_amdgcn_readfirstlane(rowptr[node + 1]);
    float ax = 0.f, ay = 0.f;
    if (half == 0) {
        unsigned u = G16[node * 32 + lc];
        ax = bflo(u); ay = bfhi(u);
    }
    int j = beg;
    for (; j + 32 <= end; j += 32) {          // full batch: 32 edges, 16 loads
        unsigned u[16]; float nv[16];
        #pragma unroll
        for (int t = 0; t < 16; ++t) {
            int2 pa = ep[j + t];              // uniform -> s_load
            int2 pb = ep[j + 16 + t];         // uniform -> s_load
            int src = half ? pb.x : pa.x;
            nv[t] = __int_as_float(half ? pb.y : pa.y);
            u[t] = G16[src * 32 + lc];
        }
        #pragma unroll
        for (int t = 0; t < 16; ++t) {
            ax = fmaf(bflo(u[t]), nv[t], ax);
            ay = fmaf(bfhi(u[t]), nv[t], ay);
        }
    }
    if (j < end) {                            // masked batch (any tail 1..31)
        unsigned u[16]; float nv[16];
        #pragma unroll
        for (int t = 0; t < 16; ++t) {
            int ia = j + t, ib = j + 16 + t;  // uniform
            int2 pa = ep[ia < end ? ia : j];
            int2 pb = ep[ib < end ? ib : j];
            int src = half ? pb.x : pa.x;
            float w = __int_as_float(half ? pb.y : pa.y);
            bool v = half ? (ib < end) : (ia < end);
            nv[t] = v ? w : 0.f;
            u[t] = G16[src * 32 + lc];
        }
        #pragma unroll
        for (int t = 0; t < 16; ++t) {
            ax = fmaf(bflo(u[t]), nv[t], ax);
            ay = fmaf(bfhi(u[t]), nv[t], ay);
        }
    }
    ax += __shfl_xor(ax, 32, 64);
    ay += __shfl_xor(ay, 32, 64);
    if (half == 0) {
        float din = dinv[node];
        float2 o = make_float2(din * ax, din * ay);
        *((float2*)(Y + (size_t)node * 64) + lc) = o;
    }
}

// G' = dinv (.) ( relu(Y + bias) @ W ), bf16 out — 4 nodes/wave, W in VGPRs. grid NN/16.
__global__ __launch_bounds__(256, 4) void k_mv(
    const float* __restrict__ Y, const float* __restrict__ dinv,
    const float* __restrict__ bias, const float* __restrict__ W,
    unsigned short* __restrict__ Gout)
{
    int lane = threadIdx.x & 63;
    int wid  = threadIdx.x >> 6;
    float w[64];
    #pragma unroll
    for (int k = 0; k < 64; ++k) w[k] = W[k * 64 + lane];
    float bl = bias[lane];
    int n0 = (blockIdx.x * 4 + wid) * 4;
    float v0 = fmaxf(Y[(n0 + 0) * 64 + lane] + bl, 0.f);
    float v1 = fmaxf(Y[(n0 + 1) * 64 + lane] + bl, 0.f);
    float v2 = fmaxf(Y[(n0 + 2) * 64 + lane] + bl, 0.f);
    float v3 = fmaxf(Y[(n0 + 3) * 64 + lane] + bl, 0.f);
    float a0 = 0.f, a1 = 0.f, a2 = 0.f, a3 = 0.f;
    #pragma unroll
    for (int k = 0; k < 64; ++k) {
        float wk = w[k];
        a0 = fmaf(RLF(v0, k), wk, a0);
        a1 = fmaf(RLF(v1, k), wk, a1);
        a2 = fmaf(RLF(v2, k), wk, a2);
        a3 = fmaf(RLF(v3, k), wk, a3);
    }
    Gout[(n0 + 0) * 64 + lane] = bf16rtn(dinv[n0 + 0] * a0);
    Gout[(n0 + 1) * 64 + lane] = bf16rtn(dinv[n0 + 1] * a1);
    Gout[(n0 + 2) * 64 + lane] = bf16rtn(dinv[n0 + 2] * a2);
    Gout[(n0 + 3) * 64 + lane] = bf16rtn(dinv[n0 + 3] * a3);
}

// out = relu(relu(Y+b5)@fW1 + fb1) @ fW2 + fb2 — 4 nodes/wave, fW1 in VGPRs. grid NN/16.
__global__ __launch_bounds__(256, 4) void k_head(
    const float* __restrict__ Y, const float* __restrict__ b5,
    const float* __restrict__ fW1, const float* __restrict__ fb1,
    const float* __restrict__ fW2, const float* __restrict__ fb2,
    float* __restrict__ out)
{
    int lane = threadIdx.x & 63;
    int wid  = threadIdx.x >> 6;
    float w[64];
    #pragma unroll
    for (int k = 0; k < 64; ++k) w[k] = fW1[k * 64 + lane];
    float bl = b5[lane], fb1l = fb1[lane], fw2l = fW2[lane], fb2s = fb2[0];
    int n0 = (blockIdx.x * 4 + wid) * 4;
    float v0 = fmaxf(Y[(n0 + 0) * 64 + lane] + bl, 0.f);
    float v1 = fmaxf(Y[(n0 + 1) * 64 + lane] + bl, 0.f);
    float v2 = fmaxf(Y[(n0 + 2) * 64 + lane] + bl, 0.f);
    float v3 = fmaxf(Y[(n0 + 3) * 64 + lane] + bl, 0.f);
    float a0 = 0.f, a1 = 0.f, a2 = 0.f, a3 = 0.f;
    #pragma unroll
    for (int k = 0; k < 64; ++k) {
        float wk = w[k];
        a0 = fmaf(RLF(v0, k), wk, a0);
        a1 = fmaf(RLF(v1, k), wk, a1);
        a2 = fmaf(RLF(v2, k), wk, a2);
        a3 = fmaf(RLF(v3, k), wk, a3);
    }
    float t0 = fmaxf(a0 + fb1l, 0.f) * fw2l;
    float t1 = fmaxf(a1 + fb1l, 0.f) * fw2l;
    float t2 = fmaxf(a2 + fb1l, 0.f) * fw2l;
    float t3 = fmaxf(a3 + fb1l, 0.f) * fw2l;
    #pragma unroll
    for (int m = 32; m >= 1; m >>= 1) {
        t0 += __shfl_xor(t0, m, 64);
        t1 += __shfl_xor(t1, m, 64);
        t2 += __shfl_xor(t2, m, 64);
        t3 += __shfl_xor(t3, m, 64);
    }
    if (lane == 0) {
        out[n0 + 0] = t0 + fb2s;
        out[n0 + 1] = t1 + fb2s;
        out[n0 + 2] = t2 + fb2s;
        out[n0 + 3] = t3 + fb2s;
    }
}

// ---------------- Launch ----------------

extern "C" void kernel_launch(void* const* d_in, const int* in_sizes, int n_in,
                              void* d_out, int out_size, void* d_ws, size_t ws_size,
                              hipStream_t stream) {
    const float* x   = (const float*)d_in[0];
    const int*   ei  = (const int*)d_in[1];
    const float* ew  = (const float*)d_in[2];
    const float* W1  = (const float*)d_in[3];
    const float* b1  = (const float*)d_in[4];
    const float* W2  = (const float*)d_in[5];
    const float* b2  = (const float*)d_in[6];
    const float* W3  = (const float*)d_in[7];
    const float* b3  = (const float*)d_in[8];
    const float* W4  = (const float*)d_in[9];
    const float* b4  = (const float*)d_in[10];
    const float* W5  = (const float*)d_in[11];
    const float* b5  = (const float*)d_in[12];
    const float* fW1 = (const float*)d_in[13];
    const float* fb1 = (const float*)d_in[14];
    const float* fW2 = (const float*)d_in[15];
    const float* fb2 = (const float*)d_in[16];
    float* out = (float*)d_out;

    char* ws = (char*)d_ws;
    size_t o = 0;
    auto alloc = [&](size_t elems) -> void* {
        void* p = (void*)(ws + o);
        o += ((elems * 4 + 255) / 256) * 256;
        return p;
    };
    float* dinv   = (float*)alloc(NN);
    float* xd     = (float*)alloc(NN);
    int*   rowptr = (int*)alloc(NN + 1);
    int*   cnt    = (int*)alloc(NN);
    int*   bsum   = (int*)alloc(128);
    int2*  epair  = (int2*)alloc(2 * (size_t)EE);
    float* Yb     = (float*)alloc((size_t)NN * 64);       // fp32 gather output
    unsigned* Ga16 = (unsigned*)alloc((size_t)NN * 32);   // bf16 feature rows
    unsigned* Gb16 = (unsigned*)alloc((size_t)NN * 32);
    int*   slot   = (int*)Yb;   // aliased: slot dead (after k_fill) before Yb first written

    int gE  = (EE + 255) / 256;
    int nb  = (NN + 1023) / 1024;    // 98
    int gW1 = NN / 4;                // 25000: 1 node/wave
    int gW4 = NN / 16;               // 6250:  4 nodes/wave

    hipMemsetAsync(cnt, 0, NN * sizeof(int), stream);
    k_count<<<gE, 256, 0, stream>>>(ei, cnt, slot);
    k_bsum<<<nb, 256, 0, stream>>>(cnt, bsum);
    k_scan_out<<<nb, 256, 0, stream>>>(cnt, bsum, rowptr);
    k_fill<<<gE, 256, 0, stream>>>(ei, ew, slot, rowptr, epair);
    k_deg<<<gW4, 256, 0, stream>>>(rowptr, epair, x, dinv, xd);

    // Layer 1 (scalar gather + matvec) -> G2' bf16
    k_l1<<<gW4, 256, 0, stream>>>(xd, dinv, rowptr, epair, W1, b1, W2,
                                  (unsigned short*)Ga16);
    // Layers 2..4
    k_gather<<<gW1, 256, 0, stream>>>(Ga16, dinv, rowptr, epair, Yb);
    k_mv<<<gW4, 256, 0, stream>>>(Yb, dinv, b2, W3, (unsigned short*)Gb16);
    k_gather<<<gW1, 256, 0, stream>>>(Gb16, dinv, rowptr, epair, Yb);
    k_mv<<<gW4, 256, 0, stream>>>(Yb, dinv, b3, W4, (unsigned short*)Ga16);
    k_gather<<<gW1, 256, 0, stream>>>(Ga16, dinv, rowptr, epair, Yb);
    k_mv<<<gW4, 256, 0, stream>>>(Yb, dinv, b4, W5, (unsigned short*)Gb16);
    // Layer 5 + head
    k_gather<<<gW1, 256, 0, stream>>>(Gb16, dinv, rowptr, epair, Yb);
    k_head<<<gW4, 256, 0, stream>>>(Yb, b5, fW1, fb1, fW2, fb2, out);
}

// Round 9
// 519.284 us; speedup vs baseline: 1.1555x; 1.1555x over previous
//
#include <hip/hip_runtime.h>
#include <hip/hip_bf16.h>

#define NN 100000
#define EE 1250000

#define RL(x, l) __builtin_amdgcn_readlane((x), (l))
#define RLF(x, l) __int_as_float(__builtin_amdgcn_readlane(__float_as_int(x), (l)))

__device__ __forceinline__ unsigned short bf16rtn(float x) {
    unsigned u = __float_as_uint(x);
    unsigned r = u + 0x7fffu + ((u >> 16) & 1u);
    return (unsigned short)(r >> 16);
}
__device__ __forceinline__ float bflo(unsigned u) { return __uint_as_float(u << 16); }
__device__ __forceinline__ float bfhi(unsigned u) { return __uint_as_float(u & 0xffff0000u); }

// ---------------- CSR build ----------------

// one returning atomic per edge: slot within dst row.
// ~50us floor: memory-side atomics write ~35B to HBM each (R5/R7/R8 measured).
__global__ __launch_bounds__(256) void k_count(const int* __restrict__ ei,
                                               int* __restrict__ cnt,
                                               int* __restrict__ slot) {
    int e = blockIdx.x * 256 + threadIdx.x;
    if (e >= EE) return;
    int d = __builtin_nontemporal_load(&ei[EE + e]);
    int s = atomicAdd(&cnt[d], 1);
    __builtin_nontemporal_store(s, &slot[e]);
}

__global__ __launch_bounds__(256) void k_bsum(const int* __restrict__ cnt, int* __restrict__ bsum) {
    __shared__ int ls[256];
    int b = blockIdx.x, tid = threadIdx.x;
    int base = b * 1024 + tid * 4;
    int s = 0;
    #pragma unroll
    for (int j = 0; j < 4; ++j) { int g = base + j; if (g < NN) s += cnt[g]; }
    ls[tid] = s; __syncthreads();
    for (int off = 128; off > 0; off >>= 1) {
        if (tid < off) ls[tid] += ls[tid + off];
        __syncthreads();
    }
    if (tid == 0) bsum[b] = ls[0];
}

// per-1024 scan; block base computed in-kernel from bsum (merged k_bscan)
__global__ __launch_bounds__(256) void k_scan_out(const int* __restrict__ cnt,
                                                  const int* __restrict__ bsum,
                                                  int* __restrict__ rowptr) {
    __shared__ int ls[256];
    __shared__ int sbase;
    int b = blockIdx.x, tid = threadIdx.x;
    if (tid < 64) {
        int w0 = (tid < b) ? bsum[tid] : 0;
        int w1 = ((64 + tid) < b) ? bsum[64 + tid] : 0;
        int s = w0 + w1;
        #pragma unroll
        for (int m = 32; m >= 1; m >>= 1) s += __shfl_xor(s, m, 64);
        if (tid == 0) sbase = s;
    }
    int base = b * 1024 + tid * 4;
    int c[4]; int s = 0;
    #pragma unroll
    for (int j = 0; j < 4; ++j) {
        int g = base + j;
        c[j] = (g < NN) ? cnt[g] : 0;
        s += c[j];
    }
    ls[tid] = s; __syncthreads();
    for (int off = 1; off < 256; off <<= 1) {
        int v = (tid >= off) ? ls[tid - off] : 0;
        __syncthreads();
        ls[tid] += v;
        __syncthreads();
    }
    int excl = ls[tid] - s + sbase;
    #pragma unroll
    for (int j = 0; j < 4; ++j) {
        int g = base + j;
        if (g < NN) {
            rowptr[g + 1] = excl + c[j];
            excl += c[j];
        }
    }
    if (b == 0 && tid == 0) rowptr[0] = 0;
}

__global__ __launch_bounds__(256) void k_fill(const int* __restrict__ ei,
                                              const float* __restrict__ ew,
                                              const int* __restrict__ slot,
                                              const int* __restrict__ rowptr,
                                              int2* __restrict__ epair) {
    int e = blockIdx.x * 256 + threadIdx.x;
    if (e >= EE) return;
    int s = __builtin_nontemporal_load(&ei[e]);
    int d = __builtin_nontemporal_load(&ei[EE + e]);
    float w = __builtin_nontemporal_load(&ew[e]);
    int sl = __builtin_nontemporal_load(&slot[e]);
    int p = rowptr[d] + sl;
    epair[p] = make_int2(s, __float_as_int(w));
}

// deg[n] = 1 + sum_row ew -> dinv[n], xd[n] = dinv[n]*x[n].  4 nodes/wave.
__global__ __launch_bounds__(256) void k_deg(const int* __restrict__ rowptr,
                                             const int2* __restrict__ epair,
                                             const float* __restrict__ x,
                                             float* __restrict__ dinv,
                                             float* __restrict__ xd) {
    int lane = threadIdx.x & 63;
    int wid  = threadIdx.x >> 6;
    int l16  = lane & 15;
    int sub  = lane >> 4;
    int node = (blockIdx.x * 4 + wid) * 4 + sub;
    if (node >= NN) return;
    int beg = rowptr[node], end = rowptr[node + 1];
    float s = 0.f;
    for (int idx = beg + l16; idx < end; idx += 16)
        s += __int_as_float(epair[idx].y);
    #pragma unroll
    for (int m = 8; m >= 1; m >>= 1) s += __shfl_xor(s, m, 64);
    if (l16 == 0) {
        float di = rsqrtf(s + 1.0f);
        dinv[node] = di;
        xd[node] = di * x[node];
    }
}

// ---------------- Layers ----------------
// Identity: Agg_l[d] = dinv_d * ( G'_l[d] + sum_e w_e * G'_l[src] ), G' = dinv (.) G.
// G' stored in bf16 (64 feats = 32 uints/row). Y and all accumulation fp32.

// Layer 1: z scalar agg + matvec, W2 via LDS (amortized over 4 nodes/wave). grid NN/16.
__global__ __launch_bounds__(256) void k_l1(
    const float* __restrict__ xd, const float* __restrict__ dinv,
    const int* __restrict__ rowptr, const int2* __restrict__ ep,
    const float* __restrict__ W1, const float* __restrict__ b1,
    const float* __restrict__ W2, unsigned short* __restrict__ Gout)
{
    __shared__ float sW[4096];
    int tid = threadIdx.x;
    #pragma unroll
    for (int i = 0; i < 16; ++i) sW[tid + i * 256] = W2[tid + i * 256];
    __syncthreads();
    int lane = tid & 63, l16 = lane & 15, sub = lane >> 4;
    int g4 = blockIdx.x * 4 + (tid >> 6);
    int nodeS = g4 * 4 + sub;
    int beg = rowptr[nodeS], end = rowptr[nodeS + 1];
    float partial = 0.f;
    for (int idx = beg + l16; idx < end; idx += 16) {
        int2 p = ep[idx];
        partial = fmaf(__int_as_float(p.y), xd[p.x], partial);
    }
    #pragma unroll
    for (int m = 8; m >= 1; m >>= 1) partial += __shfl_xor(partial, m, 64);
    float z = dinv[nodeS] * (xd[nodeS] + partial);   // valid where l16==0
    float z0 = RLF(z, 0), z1 = RLF(z, 16), z2 = RLF(z, 32), z3 = RLF(z, 48);
    float w1l = W1[lane], b1l = b1[lane];
    float v0 = fmaxf(fmaf(z0, w1l, b1l), 0.f);
    float v1 = fmaxf(fmaf(z1, w1l, b1l), 0.f);
    float v2 = fmaxf(fmaf(z2, w1l, b1l), 0.f);
    float v3 = fmaxf(fmaf(z3, w1l, b1l), 0.f);
    float a0 = 0.f, a1 = 0.f, a2 = 0.f, a3 = 0.f;
    #pragma unroll
    for (int k = 0; k < 64; ++k) {
        float wk = sW[k * 64 + lane];
        a0 = fmaf(RLF(v0, k), wk, a0);
        a1 = fmaf(RLF(v1, k), wk, a1);
        a2 = fmaf(RLF(v2, k), wk, a2);
        a3 = fmaf(RLF(v3, k), wk, a3);
    }
    int n0 = g4 * 4;
    Gout[(n0 + 0) * 64 + lane] = bf16rtn(dinv[n0 + 0] * a0);
    Gout[(n0 + 1) * 64 + lane] = bf16rtn(dinv[n0 + 1] * a1);
    Gout[(n0 + 2) * 64 + lane] = bf16rtn(dinv[n0 + 2] * a2);
    Gout[(n0 + 3) * 64 + lane] = bf16rtn(dinv[n0 + 3] * a3);
}

// Gather over bf16 rows: Y[d] = dinv_d * ( G'[d] + sum_e w_e * G'[src] ).
// TWO nodes per wave, each with its own 16-edge masked batch (8 row-loads)
// -> 16 independent row-loads in flight per wave, no launch_bounds VGPR cap
// (R8 lesson: capping VGPRs serializes the batch). ep reads wave-uniform
// (s_load + s_cselect); OOB clamps to ep[0]. Self row + final store use
// half0 lanes for node A, half1 lanes for node B. grid = NN/8.
__global__ __launch_bounds__(256) void k_gather(
    const unsigned* __restrict__ G16, const float* __restrict__ dinv,
    const int* __restrict__ rowptr, const int2* __restrict__ ep,
    float* __restrict__ Y)
{
    int tid = threadIdx.x;
    int lane = tid & 63;
    int lc = lane & 31;
    int half = lane >> 5;
    int pr = blockIdx.x * 4 + (tid >> 6);
    int nA = pr * 2, nB = nA + 1;
    int begA = __builtin_amdgcn_readfirstlane(rowptr[nA]);
    int endA = __builtin_amdgcn_readfirstlane(rowptr[nA + 1]);
    int endB = __builtin_amdgcn_readfirstlane(rowptr[nB + 1]);   // begB == endA
    float axA, ayA, axB, ayB;
    {
        int nS = half ? nB : nA;
        unsigned uS = G16[nS * 32 + lc];       // half0: self A, half1: self B
        float sx = bflo(uS), sy = bfhi(uS);
        axA = half ? 0.f : sx; ayA = half ? 0.f : sy;
        axB = half ? sx : 0.f; ayB = half ? sy : 0.f;
    }
    int jA = begA, jB = endA;
    while (jA < endA || jB < endB) {
        unsigned uA[8], uB[8]; float nvA[8], nvB[8];
        #pragma unroll
        for (int t = 0; t < 8; ++t) {
            int ia0 = jA + t, ia1 = jA + 8 + t;      // uniform
            int ib0 = jB + t, ib1 = jB + 8 + t;
            int2 pa0 = ep[ia0 < endA ? ia0 : 0];
            int2 pa1 = ep[ia1 < endA ? ia1 : 0];
            int2 pb0 = ep[ib0 < endB ? ib0 : 0];
            int2 pb1 = ep[ib1 < endB ? ib1 : 0];
            int sA = half ? pa1.x : pa0.x;
            float wA = __int_as_float(half ? pa1.y : pa0.y);
            bool vA = half ? (ia1 < endA) : (ia0 < endA);
            nvA[t] = vA ? wA : 0.f;
            uA[t] = G16[sA * 32 + lc];
            int sB = half ? pb1.x : pb0.x;
            float wB = __int_as_float(half ? pb1.y : pb0.y);
            bool vB = half ? (ib1 < endB) : (ib0 < endB);
            nvB[t] = vB ? wB : 0.f;
            uB[t] = G16[sB * 32 + lc];
        }
        #pragma unroll
        for (int t = 0; t < 8; ++t) {
            axA = fmaf(bflo(uA[t]), nvA[t], axA);
            ayA = fmaf(bfhi(uA[t]), nvA[t], ayA);
            axB = fmaf(bflo(uB[t]), nvB[t], axB);
            ayB = fmaf(bfhi(uB[t]), nvB[t], ayB);
        }
        jA = min(jA + 16, endA);
        jB = min(jB + 16, endB);
    }
    axA += __shfl_xor(axA, 32, 64);
    ayA += __shfl_xor(ayA, 32, 64);
    axB += __shfl_xor(axB, 32, 64);
    ayB += __shfl_xor(ayB, 32, 64);
    // half0 lanes store node A, half1 lanes store node B (no idle lanes)
    int nS = half ? nB : nA;
    float din = dinv[nS];
    float ox = half ? axB : axA;
    float oy = half ? ayB : ayA;
    *((float2*)(Y + (size_t)nS * 64) + lc) = make_float2(din * ox, din * oy);
}

// G' = dinv (.) ( relu(Y + bias) @ W ), bf16 out — 4 nodes/wave, W in VGPRs. grid NN/16.
__global__ __launch_bounds__(256, 4) void k_mv(
    const float* __restrict__ Y, const float* __restrict__ dinv,
    const float* __restrict__ bias, const float* __restrict__ W,
    unsigned short* __restrict__ Gout)
{
    int lane = threadIdx.x & 63;
    int wid  = threadIdx.x >> 6;
    float w[64];
    #pragma unroll
    for (int k = 0; k < 64; ++k) w[k] = W[k * 64 + lane];
    float bl = bias[lane];
    int n0 = (blockIdx.x * 4 + wid) * 4;
    float v0 = fmaxf(Y[(n0 + 0) * 64 + lane] + bl, 0.f);
    float v1 = fmaxf(Y[(n0 + 1) * 64 + lane] + bl, 0.f);
    float v2 = fmaxf(Y[(n0 + 2) * 64 + lane] + bl, 0.f);
    float v3 = fmaxf(Y[(n0 + 3) * 64 + lane] + bl, 0.f);
    float a0 = 0.f, a1 = 0.f, a2 = 0.f, a3 = 0.f;
    #pragma unroll
    for (int k = 0; k < 64; ++k) {
        float wk = w[k];
        a0 = fmaf(RLF(v0, k), wk, a0);
        a1 = fmaf(RLF(v1, k), wk, a1);
        a2 = fmaf(RLF(v2, k), wk, a2);
        a3 = fmaf(RLF(v3, k), wk, a3);
    }
    Gout[(n0 + 0) * 64 + lane] = bf16rtn(dinv[n0 + 0] * a0);
    Gout[(n0 + 1) * 64 + lane] = bf16rtn(dinv[n0 + 1] * a1);
    Gout[(n0 + 2) * 64 + lane] = bf16rtn(dinv[n0 + 2] * a2);
    Gout[(n0 + 3) * 64 + lane] = bf16rtn(dinv[n0 + 3] * a3);
}

// out = relu(relu(Y+b5)@fW1 + fb1) @ fW2 + fb2 — 4 nodes/wave, fW1 in VGPRs. grid NN/16.
__global__ __launch_bounds__(256, 4) void k_head(
    const float* __restrict__ Y, const float* __restrict__ b5,
    const float* __restrict__ fW1, const float* __restrict__ fb1,
    const float* __restrict__ fW2, const float* __restrict__ fb2,
    float* __restrict__ out)
{
    int lane = threadIdx.x & 63;
    int wid  = threadIdx.x >> 6;
    float w[64];
    #pragma unroll
    for (int k = 0; k < 64; ++k) w[k] = fW1[k * 64 + lane];
    float bl = b5[lane], fb1l = fb1[lane], fw2l = fW2[lane], fb2s = fb2[0];
    int n0 = (blockIdx.x * 4 + wid) * 4;
    float v0 = fmaxf(Y[(n0 + 0) * 64 + lane] + bl, 0.f);
    float v1 = fmaxf(Y[(n0 + 1) * 64 + lane] + bl, 0.f);
    float v2 = fmaxf(Y[(n0 + 2) * 64 + lane] + bl, 0.f);
    float v3 = fmaxf(Y[(n0 + 3) * 64 + lane] + bl, 0.f);
    float a0 = 0.f, a1 = 0.f, a2 = 0.f, a3 = 0.f;
    #pragma unroll
    for (int k = 0; k < 64; ++k) {
        float wk = w[k];
        a0 = fmaf(RLF(v0, k), wk, a0);
        a1 = fmaf(RLF(v1, k), wk, a1);
        a2 = fmaf(RLF(v2, k), wk, a2);
        a3 = fmaf(RLF(v3, k), wk, a3);
    }
    float t0 = fmaxf(a0 + fb1l, 0.f) * fw2l;
    float t1 = fmaxf(a1 + fb1l, 0.f) * fw2l;
    float t2 = fmaxf(a2 + fb1l, 0.f) * fw2l;
    float t3 = fmaxf(a3 + fb1l, 0.f) * fw2l;
    #pragma unroll
    for (int m = 32; m >= 1; m >>= 1) {
        t0 += __shfl_xor(t0, m, 64);
        t1 += __shfl_xor(t1, m, 64);
        t2 += __shfl_xor(t2, m, 64);
        t3 += __shfl_xor(t3, m, 64);
    }
    if (lane == 0) {
        out[n0 + 0] = t0 + fb2s;
        out[n0 + 1] = t1 + fb2s;
        out[n0 + 2] = t2 + fb2s;
        out[n0 + 3] = t3 + fb2s;
    }
}

// ---------------- Launch ----------------

extern "C" void kernel_launch(void* const* d_in, const int* in_sizes, int n_in,
                              void* d_out, int out_size, void* d_ws, size_t ws_size,
                              hipStream_t stream) {
    const float* x   = (const float*)d_in[0];
    const int*   ei  = (const int*)d_in[1];
    const float* ew  = (const float*)d_in[2];
    const float* W1  = (const float*)d_in[3];
    const float* b1  = (const float*)d_in[4];
    const float* W2  = (const float*)d_in[5];
    const float* b2  = (const float*)d_in[6];
    const float* W3  = (const float*)d_in[7];
    const float* b3  = (const float*)d_in[8];
    const float* W4  = (const float*)d_in[9];
    const float* b4  = (const float*)d_in[10];
    const float* W5  = (const float*)d_in[11];
    const float* b5  = (const float*)d_in[12];
    const float* fW1 = (const float*)d_in[13];
    const float* fb1 = (const float*)d_in[14];
    const float* fW2 = (const float*)d_in[15];
    const float* fb2 = (const float*)d_in[16];
    float* out = (float*)d_out;

    char* ws = (char*)d_ws;
    size_t o = 0;
    auto alloc = [&](size_t elems) -> void* {
        void* p = (void*)(ws + o);
        o += ((elems * 4 + 255) / 256) * 256;
        return p;
    };
    float* dinv   = (float*)alloc(NN);
    float* xd     = (float*)alloc(NN);
    int*   rowptr = (int*)alloc(NN + 1);
    int*   cnt    = (int*)alloc(NN);
    int*   bsum   = (int*)alloc(128);
    int2*  epair  = (int2*)alloc(2 * (size_t)EE);
    float* Yb     = (float*)alloc((size_t)NN * 64);       // fp32 gather output
    unsigned* Ga16 = (unsigned*)alloc((size_t)NN * 32);   // bf16 feature rows
    unsigned* Gb16 = (unsigned*)alloc((size_t)NN * 32);
    int*   slot   = (int*)Yb;   // aliased: slot dead (after k_fill) before Yb first written

    int gE  = (EE + 255) / 256;
    int nb  = (NN + 1023) / 1024;    // 98
    int gW2 = NN / 8;                // 12500: 2 nodes/wave gather
    int gW4 = NN / 16;               // 6250:  4 nodes/wave

    hipMemsetAsync(cnt, 0, NN * sizeof(int), stream);
    k_count<<<gE, 256, 0, stream>>>(ei, cnt, slot);
    k_bsum<<<nb, 256, 0, stream>>>(cnt, bsum);
    k_scan_out<<<nb, 256, 0, stream>>>(cnt, bsum, rowptr);
    k_fill<<<gE, 256, 0, stream>>>(ei, ew, slot, rowptr, epair);
    k_deg<<<gW4, 256, 0, stream>>>(rowptr, epair, x, dinv, xd);

    // Layer 1 (scalar gather + matvec) -> G2' bf16
    k_l1<<<gW4, 256, 0, stream>>>(xd, dinv, rowptr, epair, W1, b1, W2,
                                  (unsigned short*)Ga16);
    // Layers 2..4
    k_gather<<<gW2, 256, 0, stream>>>(Ga16, dinv, rowptr, epair, Yb);
    k_mv<<<gW4, 256, 0, stream>>>(Yb, dinv, b2, W3, (unsigned short*)Gb16);
    k_gather<<<gW2, 256, 0, stream>>>(Gb16, dinv, rowptr, epair, Yb);
    k_mv<<<gW4, 256, 0, stream>>>(Yb, dinv, b3, W4, (unsigned short*)Ga16);
    k_gather<<<gW2, 256, 0, stream>>>(Ga16, dinv, rowptr, epair, Yb);
    k_mv<<<gW4, 256, 0, stream>>>(Yb, dinv, b4, W5, (unsigned short*)Gb16);
    // Layer 5 + head
    k_gather<<<gW2, 256, 0, stream>>>(Gb16, dinv, rowptr, epair, Yb);
    k_head<<<gW4, 256, 0, stream>>>(Yb, b5, fW1, fb1, fW2, fb2, out);
}